// Round 5
// baseline (416.886 us; speedup 1.0000x reference)
//
#include <hip/hip_runtime.h>
#include <hip/hip_bf16.h>

typedef __bf16 bf16x8 __attribute__((ext_vector_type(8)));
typedef __bf16 bf16x4 __attribute__((ext_vector_type(4)));
typedef float floatx4 __attribute__((ext_vector_type(4)));

#define LDW 136  // wave-private activation row stride (bf16), 16B-aligned rows
#define PXW 40   // pre_msg row stride

// ws (bf16 elems). Packed-block MFMA-native layout:
// K128 mats: a-elem = off + mt*2048 + ks*512 + lane*8 + j  (9 mats)
// K256 mats: a-elem = off + mt*4096 + ks*512 + lane*8 + j  (2 mats)
// K32 pads:  a-elem = off + mt*512 + lane*8 + j            (4 mats)
// N16 tails: a-elem = off + ks*512 + lane*8 + j            (2 mats)
#define O_E1W2  0
#define O_E2W2  16384
#define O_E3W1  32768
#define O_E3W2  49152
#define O_E4W2  65536
#define O_DM2T0 81920
#define O_DM2T1 98304
#define O_DO1   114688
#define O_DO2   131072
#define O_E2W1  147456
#define O_E4W1  180224
#define O_E1W1P 212992
#define O_M1T0P 217088
#define O_M1T1P 221184
#define O_DO1XP 225280
#define O_EWOUT 229376
#define O_DW3   231424
#define WS_ELEMS 233472

__global__ void prep_kernel(const float* e1w2, const float* e2w2, const float* e3w1,
    const float* e3w2, const float* e4w2, const float* dmsg2, const float* dout1,
    const float* dout2, const float* e2w1, const float* e4w1, const float* e1w1,
    const float* dmsg_w1, const float* ew_out, const float* dout_w3,
    __hip_bfloat16* ws) {
  int idx = blockIdx.x * 256 + threadIdx.x;
  if (idx >= WS_ELEMS) return;
  float v = 0.f;
  if (idx < O_E2W1) {                       // nine K=128 matrices
    int mat = idx >> 14, l = idx & 16383;
    int j = l & 7, ln = (l >> 3) & 63, blk = l >> 9;
    int ks = blk & 3, mt = blk >> 2;
    int n = mt * 16 + (ln & 15);
    int k = ks * 32 + ((ln >> 4) << 3) + j;
    const float* s;
    switch (mat) {
      case 0: s = e1w2; break;  case 1: s = e2w2; break;
      case 2: s = e3w1; break;  case 3: s = e3w2; break;
      case 4: s = e4w2; break;  case 5: s = dmsg2; break;
      case 6: s = dmsg2 + 16384; break;
      case 7: s = dout1 + 384; break;
      default: s = dout2; break;
    }
    v = s[k * 128 + n];
  } else if (idx < O_E1W1P) {               // two K=256 matrices
    int l2 = idx - O_E2W1;
    int mat = l2 >> 15, l = l2 & 32767;
    int j = l & 7, ln = (l >> 3) & 63, blk = l >> 9;
    int ks = blk & 7, mt = blk >> 3;
    int n = mt * 16 + (ln & 15);
    int k = ks * 32 + ((ln >> 4) << 3) + j;
    const float* s = mat ? e4w1 : e2w1;
    v = s[k * 128 + n];
  } else if (idx < O_EWOUT) {               // four K=32 zero-padded
    int l2 = idx - O_E1W1P;
    int mat = l2 >> 12, l = l2 & 4095;
    int j = l & 7, ln = (l >> 3) & 63, mt = l >> 9;
    int n = mt * 16 + (ln & 15);
    int k = ((ln >> 4) << 3) + j;           // 0..31; pxb cols: 0..2 recv-x, 3..5 self-x
    if (mat == 0)      v = (k >= 3 && k < 6) ? e1w1[(k - 3) * 128 + n] : 0.f;
    else if (mat == 1) v = (k < 6) ? dmsg_w1[k * 128 + n] : 0.f;
    else if (mat == 2) v = (k < 6) ? dmsg_w1[768 + k * 128 + n] : 0.f;
    else               v = (k >= 3 && k < 6) ? dout1[(k - 3) * 128 + n] : 0.f;
  } else {                                  // two N=16 padded tails
    int l2 = idx - O_EWOUT;
    int mat = l2 >> 11, l = l2 & 2047;
    int j = l & 7, ln = (l >> 3) & 63, ks = l >> 9;
    int n = ln & 15;
    int k = ks * 32 + ((ln >> 4) << 3) + j;
    if (mat == 0) v = (n < 2) ? ew_out[k * 2 + n] : 0.f;
    else          v = (n < 3) ? dout_w3[k * 3 + n] : 0.f;
  }
  ws[idx] = __float2bfloat16(v);
}

union PK { bf16x4 v; __hip_bfloat16 h[4]; };

// One wave = 8 graphs = 48 rows, fully independent. No barriers after stage 0.
__global__ __launch_bounds__(256, 2) void nri_fused(
    const float* __restrict__ x,
    const float* __restrict__ e1b1, const float* __restrict__ e1b2,
    const float* __restrict__ e2b1, const float* __restrict__ e2b2,
    const float* __restrict__ e3b1, const float* __restrict__ e3b2,
    const float* __restrict__ e4b1, const float* __restrict__ e4b2,
    const float* __restrict__ eb_out,
    const float* __restrict__ dmsg_b1, const float* __restrict__ dmsg_b2,
    const float* __restrict__ dout_b1, const float* __restrict__ dout_b2,
    const float* __restrict__ dout_b3,
    const __bf16* __restrict__ wt, float* __restrict__ out)
{
  const int tid  = threadIdx.x;
  const int wave = tid >> 6;
  const int lane = tid & 63;
  const int nl   = lane & 15;
  const int quad = lane >> 4;

  __shared__ __align__(16) __hip_bfloat16 bufAll[4 * 48 * LDW];
  __shared__ __align__(16) __hip_bfloat16 pxbAll[4 * 48 * PXW];
  __shared__ float rtwAll[4 * 96];
  __shared__ float obufAll[4 * 144];
  __shared__ __align__(16) float biasL[16 * 128];

  __bf16* buf  = (__bf16*)(void*)(bufAll + wave * 48 * LDW);
  __bf16* pxb  = (__bf16*)(void*)(pxbAll + wave * 48 * PXW);
  float*  rtw  = rtwAll + wave * 96;
  float*  obuf = obufAll + wave * 144;

  const int wid = blockIdx.x * 4 + wave;
  const int gxw = wid * 144;

  // ---- stage 0: bias table (cooperative) + per-wave pre_msg/x staging ----
  for (int i = tid; i < 2048; i += 256) {
    int row = i >> 7, c = i & 127;
    float v;
    switch (row) {
      case 0: v = e1b1[c]; break;   case 1: v = e1b2[c]; break;
      case 2: v = e2b1[c]; break;   case 3: v = e2b2[c]; break;
      case 4: v = e3b1[c]; break;   case 5: v = e3b2[c]; break;
      case 6: v = e4b1[c]; break;   case 7: v = e4b2[c]; break;
      case 8: v = dmsg_b1[c]; break;  case 9: v = dmsg_b1[128 + c]; break;
      case 10: v = dmsg_b2[c]; break; case 11: v = dmsg_b2[128 + c]; break;
      case 12: v = dout_b1[c]; break; case 13: v = dout_b2[c]; break;
      case 14: v = (c < 2) ? eb_out[c] : 0.f; break;
      default: v = (c < 3) ? dout_b3[c] : 0.f; break;
    }
    biasL[i] = v;
  }
  for (int i = lane; i < 1536; i += 64) {   // 48 rows x 32 k-slots (zeroed pad)
    int row = i >> 5, c = i & 31;
    float v = 0.f;
    if (c < 3)      { int e = row % 6; int rr = row + ((e == 5) ? -5 : 1); v = x[gxw + rr * 3 + c]; }
    else if (c < 6) v = x[gxw + row * 3 + (c - 3)];
    pxb[row * PXW + c] = __float2bfloat16(v);
  }
  __syncthreads();  // the only barrier

  // ---- helpers (per wave; A=weights packed-block, B=private LDS acts) ----
  auto initA = [&](floatx4 (&acc)[8][3], int brow) {
#pragma unroll
    for (int mt = 0; mt < 8; ++mt) {
      floatx4 bv = *(const floatx4*)(biasL + brow * 128 + mt * 16 + quad * 4);
#pragma unroll
      for (int rt = 0; rt < 3; ++rt) acc[mt][rt] = bv;
    }
  };
  auto gK128 = [&](floatx4 (&acc)[8][3], int wofs) {
    const __bf16* wp = wt + wofs + lane * 8;
#pragma unroll
    for (int ks = 0; ks < 4; ++ks) {
      bf16x8 b[3];
#pragma unroll
      for (int rt = 0; rt < 3; ++rt)
        b[rt] = *(const bf16x8*)(buf + (rt * 16 + nl) * LDW + ks * 32 + quad * 8);
#pragma unroll
      for (int mt = 0; mt < 8; ++mt) {
        bf16x8 a = *(const bf16x8*)(wp + mt * 2048 + ks * 512);
#pragma unroll
        for (int rt = 0; rt < 3; ++rt)
          acc[mt][rt] = __builtin_amdgcn_mfma_f32_16x16x32_bf16(a, b[rt], acc[mt][rt], 0, 0, 0);
      }
    }
  };
  auto gK256dual = [&](floatx4 (&acc)[8][3], int wofs) {  // [recv-remap rows | self rows]
    int rof0[3], rof1[3];
#pragma unroll
    for (int rt = 0; rt < 3; ++rt) {
      int r = rt * 16 + nl;
      rof1[rt] = r * LDW;
      int e = r % 6;
      rof0[rt] = (r + ((e == 5) ? -5 : 1)) * LDW;
    }
    const __bf16* wp = wt + wofs + lane * 8;
#pragma unroll
    for (int ks = 0; ks < 8; ++ks) {
      bf16x8 b[3];
#pragma unroll
      for (int rt = 0; rt < 3; ++rt)
        b[rt] = *(const bf16x8*)(buf + ((ks < 4) ? rof0[rt] : rof1[rt]) + (ks & 3) * 32 + quad * 8);
#pragma unroll
      for (int mt = 0; mt < 8; ++mt) {
        bf16x8 a = *(const bf16x8*)(wp + mt * 4096 + ks * 512);
#pragma unroll
        for (int rt = 0; rt < 3; ++rt)
          acc[mt][rt] = __builtin_amdgcn_mfma_f32_16x16x32_bf16(a, b[rt], acc[mt][rt], 0, 0, 0);
      }
    }
  };
  auto gK256half = [&](floatx4 (&acc)[8][3], int wofs, int kh) {
    const __bf16* wp = wt + wofs + lane * 8 + kh * 4 * 512;
#pragma unroll
    for (int ks = 0; ks < 4; ++ks) {
      bf16x8 b[3];
#pragma unroll
      for (int rt = 0; rt < 3; ++rt)
        b[rt] = *(const bf16x8*)(buf + (rt * 16 + nl) * LDW + ks * 32 + quad * 8);
#pragma unroll
      for (int mt = 0; mt < 8; ++mt) {
        bf16x8 a = *(const bf16x8*)(wp + mt * 4096 + ks * 512);
#pragma unroll
        for (int rt = 0; rt < 3; ++rt)
          acc[mt][rt] = __builtin_amdgcn_mfma_f32_16x16x32_bf16(a, b[rt], acc[mt][rt], 0, 0, 0);
      }
    }
  };
  auto gK32 = [&](floatx4 (&acc)[8][3], int wofs) {
    const __bf16* wp = wt + wofs + lane * 8;
    bf16x8 b[3];
#pragma unroll
    for (int rt = 0; rt < 3; ++rt)
      b[rt] = *(const bf16x8*)(pxb + (rt * 16 + nl) * PXW + quad * 8);
#pragma unroll
    for (int mt = 0; mt < 8; ++mt) {
      bf16x8 a = *(const bf16x8*)(wp + mt * 512);
#pragma unroll
      for (int rt = 0; rt < 3; ++rt)
        acc[mt][rt] = __builtin_amdgcn_mfma_f32_16x16x32_bf16(a, b[rt], acc[mt][rt], 0, 0, 0);
    }
  };
  auto storeA = [&](floatx4 (&acc)[8][3], int act) {  // 1=ELU 2=ReLU
#pragma unroll
    for (int mt = 0; mt < 8; ++mt)
#pragma unroll
      for (int rt = 0; rt < 3; ++rt) {
        PK p;
#pragma unroll
        for (int r = 0; r < 4; ++r) {
          float z = acc[mt][rt][r];
          if (act == 1) z = (z > 0.f) ? z : (__expf(z) - 1.f);
          else z = fmaxf(z, 0.f);
          p.h[r] = __float2bfloat16(z);
        }
        *(bf16x4*)(buf + (rt * 16 + nl) * LDW + mt * 16 + quad * 4) = p.v;
      }
  };

  floatx4 acc[8][3];

  // s1: ELU(x @ e1w1 + b)          (K=32 from pxb)
  initA(acc, 0); gK32(acc, O_E1W1P); storeA(acc, 1);
  // s2: h = ELU(. @ e1w2 + b)
  initA(acc, 1); gK128(acc, O_E1W2); storeA(acc, 1);
  // s3: ELU([h_recv|h] @ e2w1 + b) (K=256)
  initA(acc, 2); gK256dual(acc, O_E2W1); storeA(acc, 1);
  // s4: he = ELU(. @ e2w2 + b)  -> buf + register stash
  bf16x4 stash[8][3];
  initA(acc, 3); gK128(acc, O_E2W2);
#pragma unroll
  for (int mt = 0; mt < 8; ++mt)
#pragma unroll
    for (int rt = 0; rt < 3; ++rt) {
      PK p;
#pragma unroll
      for (int r = 0; r < 4; ++r) {
        float z = acc[mt][rt][r];
        z = (z > 0.f) ? z : (__expf(z) - 1.f);
        p.h[r] = __float2bfloat16(z);
      }
      stash[mt][rt] = p.v;
      *(bf16x4*)(buf + (rt * 16 + nl) * LDW + mt * 16 + quad * 4) = p.v;
    }
  // s5: ELU(he @ e3w1 + b)
  initA(acc, 4); gK128(acc, O_E3W1); storeA(acc, 1);
  // s6: h2 = ELU(. @ e3w2 + b)
  initA(acc, 5); gK128(acc, O_E3W2); storeA(acc, 1);
  // s7: ELU([h2|he] @ e4w1 + b): pass1 on h2 (buf), restore he, pass2
  initA(acc, 6); gK256half(acc, O_E4W1, 0);
#pragma unroll
  for (int mt = 0; mt < 8; ++mt)
#pragma unroll
    for (int rt = 0; rt < 3; ++rt)
      *(bf16x4*)(buf + (rt * 16 + nl) * LDW + mt * 16 + quad * 4) = stash[mt][rt];
  gK256half(acc, O_E4W1, 1); storeA(acc, 1);
  // s8: h3 = ELU(. @ e4w2 + b)
  initA(acc, 7); gK128(acc, O_E4W2); storeA(acc, 1);

  // s9: logits (N=16 padded tail); raw -> rtw
  {
    floatx4 lg[3];
    const __bf16* wp = wt + O_EWOUT + lane * 8;
#pragma unroll
    for (int rt = 0; rt < 3; ++rt) lg[rt] = *(const floatx4*)(biasL + 14 * 128 + quad * 4);
#pragma unroll
    for (int ks = 0; ks < 4; ++ks) {
      bf16x8 a = *(const bf16x8*)(wp + ks * 512);
#pragma unroll
      for (int rt = 0; rt < 3; ++rt) {
        bf16x8 b = *(const bf16x8*)(buf + (rt * 16 + nl) * LDW + ks * 32 + quad * 8);
        lg[rt] = __builtin_amdgcn_mfma_f32_16x16x32_bf16(a, b, lg[rt], 0, 0, 0);
      }
    }
    if (quad == 0) {
#pragma unroll
      for (int rt = 0; rt < 3; ++rt) {
        int row = rt * 16 + nl;
        rtw[row * 2] = lg[rt][0]; rtw[row * 2 + 1] = lg[rt][1];
      }
    }
  }
  // s10a: m1(t0) = relu(pre_msg @ w1t0 + b)
  initA(acc, 8); gK32(acc, O_M1T0P); storeA(acc, 2);
  // softmax weights per owned row
  float w0[3], w1[3];
#pragma unroll
  for (int rt = 0; rt < 3; ++rt) {
    int row = rt * 16 + nl;
    float l0 = rtw[row * 2], l1 = rtw[row * 2 + 1];
    float mx = fmaxf(l0, l1);
    float e0 = __expf(l0 - mx), e1 = __expf(l1 - mx);
    float inv = 1.f / (e0 + e1);
    w0[rt] = e0 * inv; w1[rt] = e1 * inv;
  }
  // s11a: msg = w0 * relu(m1t0 @ w2t0 + b)
  floatx4 msg[8][3];
  initA(acc, 10); gK128(acc, O_DM2T0);
#pragma unroll
  for (int mt = 0; mt < 8; ++mt)
#pragma unroll
    for (int rt = 0; rt < 3; ++rt)
#pragma unroll
      for (int r = 0; r < 4; ++r)
        msg[mt][rt][r] = w0[rt] * fmaxf(acc[mt][rt][r], 0.f);
  // s10b: m1(t1)
  initA(acc, 9); gK32(acc, O_M1T1P); storeA(acc, 2);
  // s11b: msg += w1 * relu(m1t1 @ w2t1 + b)
  initA(acc, 11); gK128(acc, O_DM2T1);
#pragma unroll
  for (int mt = 0; mt < 8; ++mt)
#pragma unroll
    for (int rt = 0; rt < 3; ++rt)
#pragma unroll
      for (int r = 0; r < 4; ++r)
        msg[mt][rt][r] += w1[rt] * fmaxf(acc[mt][rt][r], 0.f);
  // s12-pre: agg (edge e -> node (e+1)%6) -> buf
#pragma unroll
  for (int mt = 0; mt < 8; ++mt)
#pragma unroll
    for (int rt = 0; rt < 3; ++rt) {
      int row = rt * 16 + nl;
      int e = row % 6;
      int orow = row + ((e == 5) ? -5 : 1);
      PK p;
#pragma unroll
      for (int r = 0; r < 4; ++r) p.h[r] = __float2bfloat16(msg[mt][rt][r]);
      *(bf16x4*)(buf + orow * LDW + mt * 16 + quad * 4) = p.v;
    }
  // s12: p1 = relu([x|agg] @ d_out_w1 + b)
  initA(acc, 12); gK128(acc, O_DO1); gK32(acc, O_DO1XP); storeA(acc, 2);
  // s13: p2 = relu(. @ d_out_w2 + b)
  initA(acc, 13); gK128(acc, O_DO2); storeA(acc, 2);
  // s14: out = x + p2 @ d_out_w3 + b3
  {
    floatx4 d[3];
    const __bf16* wp = wt + O_DW3 + lane * 8;
#pragma unroll
    for (int rt = 0; rt < 3; ++rt) d[rt] = *(const floatx4*)(biasL + 15 * 128 + quad * 4);
#pragma unroll
    for (int ks = 0; ks < 4; ++ks) {
      bf16x8 a = *(const bf16x8*)(wp + ks * 512);
#pragma unroll
      for (int rt = 0; rt < 3; ++rt) {
        bf16x8 b = *(const bf16x8*)(buf + (rt * 16 + nl) * LDW + ks * 32 + quad * 8);
        d[rt] = __builtin_amdgcn_mfma_f32_16x16x32_bf16(a, b, d[rt], 0, 0, 0);
      }
    }
    if (quad == 0) {
#pragma unroll
      for (int rt = 0; rt < 3; ++rt) {
        int row = rt * 16 + nl;
#pragma unroll
        for (int r = 0; r < 3; ++r)
          obuf[row * 3 + r] = x[gxw + row * 3 + r] + d[rt][r];
      }
    }
  }
  for (int i = lane; i < 144; i += 64) out[gxw + i] = obuf[i];
}

extern "C" void kernel_launch(void* const* d_in, const int* in_sizes, int n_in,
                              void* d_out, int out_size, void* d_ws, size_t ws_size,
                              hipStream_t stream) {
  const float* x       = (const float*)d_in[0];
  const float* e1w1    = (const float*)d_in[3];
  const float* e1b1    = (const float*)d_in[4];
  const float* e1w2    = (const float*)d_in[5];
  const float* e1b2    = (const float*)d_in[6];
  const float* e2w1    = (const float*)d_in[7];
  const float* e2b1    = (const float*)d_in[8];
  const float* e2w2    = (const float*)d_in[9];
  const float* e2b2    = (const float*)d_in[10];
  const float* e3w1    = (const float*)d_in[11];
  const float* e3b1    = (const float*)d_in[12];
  const float* e3w2    = (const float*)d_in[13];
  const float* e3b2    = (const float*)d_in[14];
  const float* e4w1    = (const float*)d_in[15];
  const float* e4b1    = (const float*)d_in[16];
  const float* e4w2    = (const float*)d_in[17];
  const float* e4b2    = (const float*)d_in[18];
  const float* ew_out  = (const float*)d_in[19];
  const float* eb_out  = (const float*)d_in[20];
  const float* dmsg_w1 = (const float*)d_in[21];
  const float* dmsg_b1 = (const float*)d_in[22];
  const float* dmsg_w2 = (const float*)d_in[23];
  const float* dmsg_b2 = (const float*)d_in[24];
  const float* dout_w1 = (const float*)d_in[25];
  const float* dout_b1 = (const float*)d_in[26];
  const float* dout_w2 = (const float*)d_in[27];
  const float* dout_b2 = (const float*)d_in[28];
  const float* dout_w3 = (const float*)d_in[29];
  const float* dout_b3 = (const float*)d_in[30];

  prep_kernel<<<(WS_ELEMS + 255) / 256, 256, 0, stream>>>(
      e1w2, e2w2, e3w1, e3w2, e4w2, dmsg_w2, dout_w1, dout_w2,
      e2w1, e4w1, e1w1, dmsg_w1, ew_out, dout_w3, (__hip_bfloat16*)d_ws);

  nri_fused<<<32768 / 32, 256, 0, stream>>>(
      x, e1b1, e1b2, e2b1, e2b2, e3b1, e3b2, e4b1, e4b2, eb_out,
      dmsg_b1, dmsg_b2, dout_b1, dout_b2, dout_b3,
      (const __bf16*)d_ws, (float*)d_out);
}

// Round 7
// 292.440 us; speedup vs baseline: 1.4255x; 1.4255x over previous
//
#include <hip/hip_runtime.h>
#include <hip/hip_bf16.h>

typedef __bf16 bf16x8 __attribute__((ext_vector_type(8)));
typedef float floatx4 __attribute__((ext_vector_type(4)));

#define LDW 136  // activation row stride
#define PXW 40   // pre_msg row stride (cols 0..2 recv-x, 3..5 self-x, rest pad)

// ws layout (bf16 element offsets). Big mats: Wt[n][k]. K32 pads: [128 n][32 k].
// N16 tails: [16 n][128 k].
#define O_E1W2  0
#define O_E2W1  16384
#define O_E2W2  49152
#define O_E3W1  65536
#define O_E3W2  81920
#define O_E4W1  98304
#define O_E4W2  131072
#define O_DM2T0 147456
#define O_DM2T1 163840
#define O_DO1   180224
#define O_DO2   196608
#define O_EWOUT 212992
#define O_DW3   215040
#define O_E1W1P 217088
#define O_M1T0P 221184
#define O_M1T1P 225280
#define O_DO1XP 229376
#define WS_ELEMS 233472

__global__ void prep_kernel(const float* e1w2, const float* e2w1, const float* e2w2,
    const float* e3w1, const float* e3w2, const float* e4w1, const float* e4w2,
    const float* dmsg2, const float* dout1, const float* dout2,
    const float* ew_out, const float* dout_w3, const float* e1w1,
    const float* dmsg_w1, __hip_bfloat16* ws) {
  int idx = blockIdx.x * 256 + threadIdx.x;
  if (idx >= WS_ELEMS) return;
  float v;
  if (idx < O_E2W1)      { int l = idx;           v = e1w2[(l & 127) * 128 + (l >> 7)]; }
  else if (idx < O_E2W2) { int l = idx - O_E2W1;  v = e2w1[(l & 255) * 128 + (l >> 8)]; }
  else if (idx < O_E3W1) { int l = idx - O_E2W2;  v = e2w2[(l & 127) * 128 + (l >> 7)]; }
  else if (idx < O_E3W2) { int l = idx - O_E3W1;  v = e3w1[(l & 127) * 128 + (l >> 7)]; }
  else if (idx < O_E4W1) { int l = idx - O_E3W2;  v = e3w2[(l & 127) * 128 + (l >> 7)]; }
  else if (idx < O_E4W2) { int l = idx - O_E4W1;  v = e4w1[(l & 255) * 128 + (l >> 8)]; }
  else if (idx < O_DM2T0){ int l = idx - O_E4W2;  v = e4w2[(l & 127) * 128 + (l >> 7)]; }
  else if (idx < O_DM2T1){ int l = idx - O_DM2T0; v = dmsg2[(l & 127) * 128 + (l >> 7)]; }
  else if (idx < O_DO1)  { int l = idx - O_DM2T1; v = dmsg2[16384 + (l & 127) * 128 + (l >> 7)]; }
  else if (idx < O_DO2)  { int l = idx - O_DO1;   v = dout1[384 + (l & 127) * 128 + (l >> 7)]; }
  else if (idx < O_EWOUT){ int l = idx - O_DO2;   v = dout2[(l & 127) * 128 + (l >> 7)]; }
  else if (idx < O_DW3)  { int l = idx - O_EWOUT; int n = l >> 7;
                           v = (n < 2) ? ew_out[(l & 127) * 2 + n] : 0.f; }
  else if (idx < O_E1W1P){ int l = idx - O_DW3;   int n = l >> 7;
                           v = (n < 3) ? dout_w3[(l & 127) * 3 + n] : 0.f; }
  else if (idx < O_M1T0P){ int l = idx - O_E1W1P; int n = l >> 5, c = l & 31;
                           v = (c >= 3 && c < 6) ? e1w1[(c - 3) * 128 + n] : 0.f; }
  else if (idx < O_M1T1P){ int l = idx - O_M1T0P; int n = l >> 5, c = l & 31;
                           v = (c < 6) ? dmsg_w1[c * 128 + n] : 0.f; }
  else if (idx < O_DO1XP){ int l = idx - O_M1T1P; int n = l >> 5, c = l & 31;
                           v = (c < 6) ? dmsg_w1[768 + c * 128 + n] : 0.f; }
  else                   { int l = idx - O_DO1XP; int n = l >> 5, c = l & 31;
                           v = (c >= 3 && c < 6) ? dout1[(c - 3) * 128 + n] : 0.f; }
  ws[idx] = __float2bfloat16(v);
}

// R2 geometry: 16 graphs/WG (96 rows), 4 waves each owning 32 cols, acts in A.
__global__ __launch_bounds__(256, 2) void nri_fused(
    const float* __restrict__ x,
    const float* __restrict__ e1b1, const float* __restrict__ e1b2,
    const float* __restrict__ e2b1, const float* __restrict__ e2b2,
    const float* __restrict__ e3b1, const float* __restrict__ e3b2,
    const float* __restrict__ e4b1, const float* __restrict__ e4b2,
    const float* __restrict__ eb_out,
    const float* __restrict__ dmsg_b1, const float* __restrict__ dmsg_b2,
    const float* __restrict__ dout_b1, const float* __restrict__ dout_b2,
    const float* __restrict__ dout_b3,
    const __bf16* __restrict__ wt, float* __restrict__ out)
{
  const int tid  = threadIdx.x;
  const int wave = tid >> 6;
  const int lane = tid & 63;
  const int nl   = lane & 15;
  const int quad = lane >> 4;
  const int gx   = blockIdx.x * 288;

  __shared__ __align__(16) __hip_bfloat16 bufA[96 * LDW];
  __shared__ __align__(16) __hip_bfloat16 bufB[96 * LDW];
  __shared__ __align__(16) __hip_bfloat16 pxb[96 * PXW];
  __shared__ __align__(16) float biasL[16 * 128];
  __shared__ float rtw[192];
  __shared__ float xs[288];
  __shared__ float obuf[288];

  // ---- stage 0: stage x, bias table, pre_msg ----
  // NOTE: 288 > 256 threads -> MUST be grid-stride loops (R6 bug: `if (tid<288)`
  // silently dropped elements 256..287 -> absmax 4.56).
  for (int i = tid; i < 288; i += 256) xs[i] = x[gx + i];
  for (int i = tid; i < 2048; i += 256) {
    int row = i >> 7, c = i & 127;
    float v;
    switch (row) {
      case 0: v = e1b1[c]; break;   case 1: v = e1b2[c]; break;
      case 2: v = e2b1[c]; break;   case 3: v = e2b2[c]; break;
      case 4: v = e3b1[c]; break;   case 5: v = e3b2[c]; break;
      case 6: v = e4b1[c]; break;   case 7: v = e4b2[c]; break;
      case 8: v = dmsg_b1[c]; break;  case 9: v = dmsg_b1[128 + c]; break;
      case 10: v = dmsg_b2[c]; break; case 11: v = dmsg_b2[128 + c]; break;
      case 12: v = dout_b1[c]; break; case 13: v = dout_b2[c]; break;
      case 14: v = (c < 2) ? eb_out[c] : 0.f; break;
      default: v = (c < 3) ? dout_b3[c] : 0.f; break;
    }
    biasL[i] = v;
  }
  for (int i = tid; i < 96 * 32; i += 256) {
    int row = i >> 5, c = i & 31;
    int e = row % 6;
    float v = 0.f;
    if (c < 3)      { int rr = row + ((e == 5) ? -5 : 1); v = x[gx + rr * 3 + c]; }
    else if (c < 6) v = x[gx + row * 3 + (c - 3)];
    pxb[row * PXW + c] = __float2bfloat16(v);
  }
  __syncthreads();

  auto initb = [&](floatx4 (&a)[6][2], int brow) {
#pragma unroll
    for (int nt = 0; nt < 2; ++nt) {
      float bv = biasL[brow * 128 + wave * 32 + nt * 16 + nl];
      floatx4 v = {bv, bv, bv, bv};
#pragma unroll
      for (int mt = 0; mt < 6; ++mt) a[mt][nt] = v;
    }
  };

  auto gemm128 = [&](floatx4 (&acc)[6][2], const __hip_bfloat16* in, const __bf16* w) {
    const __bf16* ab = (const __bf16*)(const void*)in;
    const __bf16* w0 = w + (wave * 32 + nl) * 128 + quad * 8;
    const __bf16* w1 = w0 + 16 * 128;
#pragma unroll
    for (int ks = 0; ks < 4; ++ks) {
      int kk = ks * 32 + quad * 8;
      bf16x8 b0 = *(const bf16x8*)(w0 + ks * 32);
      bf16x8 b1 = *(const bf16x8*)(w1 + ks * 32);
#pragma unroll
      for (int mt = 0; mt < 6; ++mt) {
        bf16x8 a = *(const bf16x8*)(ab + (mt * 16 + nl) * LDW + kk);
        acc[mt][0] = __builtin_amdgcn_mfma_f32_16x16x32_bf16(a, b0, acc[mt][0], 0, 0, 0);
        acc[mt][1] = __builtin_amdgcn_mfma_f32_16x16x32_bf16(a, b1, acc[mt][1], 0, 0, 0);
      }
    }
  };

  auto gemm256 = [&](floatx4 (&acc)[6][2], const __hip_bfloat16* in0, bool recv0,
                     const __hip_bfloat16* in1, const __bf16* w) {
    int rofs0[6], rofs1[6];
#pragma unroll
    for (int mt = 0; mt < 6; ++mt) {
      int r = mt * 16 + nl;
      rofs1[mt] = r * LDW;
      if (recv0) { int e = r % 6; r += (e == 5) ? -5 : 1; }
      rofs0[mt] = r * LDW;
    }
    const __bf16* ab0 = (const __bf16*)(const void*)in0;
    const __bf16* ab1 = (const __bf16*)(const void*)in1;
    const __bf16* w0 = w + (wave * 32 + nl) * 256 + quad * 8;
    const __bf16* w1 = w0 + 16 * 256;
#pragma unroll
    for (int ks = 0; ks < 8; ++ks) {
      int kk = (ks & 3) * 32 + quad * 8;
      const __bf16* ab = (ks < 4) ? ab0 : ab1;
      const int* rofs = (ks < 4) ? rofs0 : rofs1;
      bf16x8 b0 = *(const bf16x8*)(w0 + ks * 32);
      bf16x8 b1 = *(const bf16x8*)(w1 + ks * 32);
#pragma unroll
      for (int mt = 0; mt < 6; ++mt) {
        bf16x8 a = *(const bf16x8*)(ab + rofs[mt] + kk);
        acc[mt][0] = __builtin_amdgcn_mfma_f32_16x16x32_bf16(a, b0, acc[mt][0], 0, 0, 0);
        acc[mt][1] = __builtin_amdgcn_mfma_f32_16x16x32_bf16(a, b1, acc[mt][1], 0, 0, 0);
      }
    }
  };

  // K=32 GEMM: A from pxb, B from padded weight [128][32]
  auto gemm32 = [&](floatx4 (&acc)[6][2], int wofs) {
    const __bf16* pb = (const __bf16*)(const void*)pxb;
    const __bf16* wp = wt + wofs + (wave * 32 + nl) * 32 + quad * 8;
    bf16x8 b0 = *(const bf16x8*)(wp);
    bf16x8 b1 = *(const bf16x8*)(wp + 512);
#pragma unroll
    for (int mt = 0; mt < 6; ++mt) {
      bf16x8 a = *(const bf16x8*)(pb + (mt * 16 + nl) * PXW + quad * 8);
      acc[mt][0] = __builtin_amdgcn_mfma_f32_16x16x32_bf16(a, b0, acc[mt][0], 0, 0, 0);
      acc[mt][1] = __builtin_amdgcn_mfma_f32_16x16x32_bf16(a, b1, acc[mt][1], 0, 0, 0);
    }
  };

  // act: 1=ELU 2=ReLU (bias already in acc)
  auto store_act = [&](floatx4 (&acc)[6][2], int act, __hip_bfloat16* ob) {
#pragma unroll
    for (int nt = 0; nt < 2; ++nt) {
      int col = wave * 32 + nt * 16 + nl;
#pragma unroll
      for (int mt = 0; mt < 6; ++mt)
#pragma unroll
        for (int r = 0; r < 4; ++r) {
          float z = acc[mt][nt][r];
          if (act == 1) z = (z > 0.f) ? z : (__expf(z) - 1.f);
          else z = fmaxf(z, 0.f);
          ob[(mt * 16 + quad * 4 + r) * LDW + col] = __float2bfloat16(z);
        }
    }
  };

  floatx4 acc[6][2];

  // s1: hh = ELU(x @ e1w1 + b) via K=32 MFMA
  initb(acc, 0); gemm32(acc, O_E1W1P); store_act(acc, 1, bufA);
  __syncthreads();
  // s2: h = ELU(. @ e1w2 + b)
  initb(acc, 1); gemm128(acc, bufA, wt + O_E1W2); store_act(acc, 1, bufB);
  __syncthreads();
  // s3: ELU([h_recv|h] @ e2w1 + b)
  initb(acc, 2); gemm256(acc, bufB, true, bufB, wt + O_E2W1); store_act(acc, 1, bufA);
  __syncthreads();
  // s4: he = ELU(. @ e2w2 + b) -> bufB (keep)
  initb(acc, 3); gemm128(acc, bufA, wt + O_E2W2); store_act(acc, 1, bufB);
  __syncthreads();
  // s5: ELU(he @ e3w1 + b) -> bufA
  initb(acc, 4); gemm128(acc, bufB, wt + O_E3W1); store_act(acc, 1, bufA);
  __syncthreads();
  // s6: h2 = ELU(. @ e3w2 + b) -> bufA in-place
  initb(acc, 5); gemm128(acc, bufA, wt + O_E3W2);
  __syncthreads();
  store_act(acc, 1, bufA);
  __syncthreads();
  // s7: ELU([h2|he] @ e4w1 + b) -> bufA in-place
  initb(acc, 6); gemm256(acc, bufA, false, bufB, wt + O_E4W1);
  __syncthreads();
  store_act(acc, 1, bufA);
  __syncthreads();
  // s8: h3 = ELU(. @ e4w2 + b) -> bufB
  initb(acc, 7); gemm128(acc, bufA, wt + O_E4W2); store_act(acc, 1, bufB);
  __syncthreads();

  // s9: logits via N=16-padded MFMA tail (waves 0..2, 2 row-tiles each)
  if (wave < 3) {
#pragma unroll
    for (int tt = 0; tt < 2; ++tt) {
      int tile = wave * 2 + tt;
      float bv = biasL[14 * 128 + nl];
      floatx4 lg = {bv, bv, bv, bv};
      const __bf16* ab = (const __bf16*)(const void*)bufB;
      const __bf16* wp = wt + O_EWOUT + nl * 128 + quad * 8;
#pragma unroll
      for (int ks = 0; ks < 4; ++ks) {
        bf16x8 a = *(const bf16x8*)(ab + (tile * 16 + nl) * LDW + ks * 32 + quad * 8);
        bf16x8 b = *(const bf16x8*)(wp + ks * 32);
        lg = __builtin_amdgcn_mfma_f32_16x16x32_bf16(a, b, lg, 0, 0, 0);
      }
      if (nl < 2) {
#pragma unroll
        for (int r = 0; r < 4; ++r)
          rtw[(tile * 16 + quad * 4 + r) * 2 + nl] = lg[r];
      }
    }
  }
  __syncthreads();

  // s10: softmax (tid<96) + m1 both types via K=32 MFMA: t0->bufA, t1->bufB
  if (tid < 96) {
    float l0 = rtw[tid * 2], l1 = rtw[tid * 2 + 1];
    float mx = fmaxf(l0, l1);
    float ea = __expf(l0 - mx), eb = __expf(l1 - mx);
    float inv = 1.f / (ea + eb);
    rtw[tid * 2] = ea * inv; rtw[tid * 2 + 1] = eb * inv;
  }
  {
    floatx4 acc1[6][2];
    initb(acc, 8);  gemm32(acc, O_M1T0P);  store_act(acc, 2, bufA);
    initb(acc1, 9); gemm32(acc1, O_M1T1P); store_act(acc1, 2, bufB);
    __syncthreads();

    // s11: msg = rt0*relu(dm2t0 . m1t0) + rt1*relu(dm2t1 . m1t1)
    initb(acc, 10);  gemm128(acc, bufA, wt + O_DM2T0);
    initb(acc1, 11); gemm128(acc1, bufB, wt + O_DM2T1);
#pragma unroll
    for (int mt = 0; mt < 6; ++mt)
#pragma unroll
      for (int r = 0; r < 4; ++r) {
        int row = mt * 16 + quad * 4 + r;
        float r0 = rtw[row * 2], r1 = rtw[row * 2 + 1];
#pragma unroll
        for (int nt = 0; nt < 2; ++nt)
          acc[mt][nt][r] = r0 * fmaxf(acc[mt][nt][r], 0.f)
                         + r1 * fmaxf(acc1[mt][nt][r], 0.f);
      }
  }
  __syncthreads();

  // s12: agg (edge e -> node (e+1)%6) -> bufA
#pragma unroll
  for (int nt = 0; nt < 2; ++nt) {
    int col = wave * 32 + nt * 16 + nl;
#pragma unroll
    for (int mt = 0; mt < 6; ++mt)
#pragma unroll
      for (int r = 0; r < 4; ++r) {
        int row = mt * 16 + quad * 4 + r;
        int e = row % 6;
        int orow = row + ((e == 5) ? -5 : 1);
        bufA[orow * LDW + col] = __float2bfloat16(acc[mt][nt][r]);
      }
  }
  __syncthreads();

  // s13: p1 = relu([x|agg] @ d_out_w1 + b) -> bufB  (K=128 MFMA + K=32 MFMA)
  initb(acc, 12); gemm128(acc, bufA, wt + O_DO1); gemm32(acc, O_DO1XP);
  store_act(acc, 2, bufB);
  __syncthreads();
  // s14: p2 = relu(. @ d_out_w2 + b) -> bufA
  initb(acc, 13); gemm128(acc, bufB, wt + O_DO2); store_act(acc, 2, bufA);
  __syncthreads();

  // s15: out = x + p2 @ d_out_w3 + b3 via N=16-padded MFMA tail
  if (wave < 3) {
#pragma unroll
    for (int tt = 0; tt < 2; ++tt) {
      int tile = wave * 2 + tt;
      float bv = biasL[15 * 128 + nl];
      floatx4 d = {bv, bv, bv, bv};
      const __bf16* ab = (const __bf16*)(const void*)bufA;
      const __bf16* wp = wt + O_DW3 + nl * 128 + quad * 8;
#pragma unroll
      for (int ks = 0; ks < 4; ++ks) {
        bf16x8 a = *(const bf16x8*)(ab + (tile * 16 + nl) * LDW + ks * 32 + quad * 8);
        bf16x8 b = *(const bf16x8*)(wp + ks * 32);
        d = __builtin_amdgcn_mfma_f32_16x16x32_bf16(a, b, d, 0, 0, 0);
      }
      if (nl < 3) {
#pragma unroll
        for (int r = 0; r < 4; ++r) {
          int row = tile * 16 + quad * 4 + r;
          obuf[row * 3 + nl] = xs[row * 3 + nl] + d[r];
        }
      }
    }
  }
  __syncthreads();
  for (int i = tid; i < 288; i += 256) out[gx + i] = obuf[i];
}

extern "C" void kernel_launch(void* const* d_in, const int* in_sizes, int n_in,
                              void* d_out, int out_size, void* d_ws, size_t ws_size,
                              hipStream_t stream) {
  const float* x       = (const float*)d_in[0];
  const float* e1w1    = (const float*)d_in[3];
  const float* e1b1    = (const float*)d_in[4];
  const float* e1w2    = (const float*)d_in[5];
  const float* e1b2    = (const float*)d_in[6];
  const float* e2w1    = (const float*)d_in[7];
  const float* e2b1    = (const float*)d_in[8];
  const float* e2w2    = (const float*)d_in[9];
  const float* e2b2    = (const float*)d_in[10];
  const float* e3w1    = (const float*)d_in[11];
  const float* e3b1    = (const float*)d_in[12];
  const float* e3w2    = (const float*)d_in[13];
  const float* e3b2    = (const float*)d_in[14];
  const float* e4w1    = (const float*)d_in[15];
  const float* e4b1    = (const float*)d_in[16];
  const float* e4w2    = (const float*)d_in[17];
  const float* e4b2    = (const float*)d_in[18];
  const float* ew_out  = (const float*)d_in[19];
  const float* eb_out  = (const float*)d_in[20];
  const float* dmsg_w1 = (const float*)d_in[21];
  const float* dmsg_b1 = (const float*)d_in[22];
  const float* dmsg_w2 = (const float*)d_in[23];
  const float* dmsg_b2 = (const float*)d_in[24];
  const float* dout_w1 = (const float*)d_in[25];
  const float* dout_b1 = (const float*)d_in[26];
  const float* dout_w2 = (const float*)d_in[27];
  const float* dout_b2 = (const float*)d_in[28];
  const float* dout_w3 = (const float*)d_in[29];
  const float* dout_b3 = (const float*)d_in[30];

  prep_kernel<<<(WS_ELEMS + 255) / 256, 256, 0, stream>>>(
      e1w2, e2w1, e2w2, e3w1, e3w2, e4w1, e4w2, dmsg_w2, dout_w1, dout_w2,
      ew_out, dout_w3, e1w1, dmsg_w1, (__hip_bfloat16*)d_ws);

  nri_fused<<<32768 / 16, 256, 0, stream>>>(
      x, e1b1, e1b2, e2b1, e2b2, e3b1, e3b2, e4b1, e4b2, eb_out,
      dmsg_b1, dmsg_b2, dout_b1, dout_b2, dout_b3,
      (const __bf16*)d_ws, (float*)d_out);
}

// Round 8
// 276.720 us; speedup vs baseline: 1.5065x; 1.0568x over previous
//
#include <hip/hip_runtime.h>
#include <hip/hip_bf16.h>

typedef __bf16 bf16x8 __attribute__((ext_vector_type(8)));
typedef float floatx4 __attribute__((ext_vector_type(4)));

#define LDW 136  // activation row stride
#define PXW 40   // pre_msg row stride (cols 0..2 recv-x, 3..5 self-x, rest pad)

// ws layout (bf16 element offsets). Big mats: Wt[n][k]. K32 pads: [128 n][32 k].
// N16 tails: [16 n][128 k].
#define O_E1W2  0
#define O_E2W1  16384
#define O_E2W2  49152
#define O_E3W1  65536
#define O_E3W2  81920
#define O_E4W1  98304
#define O_E4W2  131072
#define O_DM2T0 147456
#define O_DM2T1 163840
#define O_DO1   180224
#define O_DO2   196608
#define O_EWOUT 212992
#define O_DW3   215040
#define O_E1W1P 217088
#define O_M1T0P 221184
#define O_M1T1P 225280
#define O_DO1XP 229376
#define WS_ELEMS 233472

__global__ void prep_kernel(const float* e1w2, const float* e2w1, const float* e2w2,
    const float* e3w1, const float* e3w2, const float* e4w1, const float* e4w2,
    const float* dmsg2, const float* dout1, const float* dout2,
    const float* ew_out, const float* dout_w3, const float* e1w1,
    const float* dmsg_w1, __hip_bfloat16* ws) {
  int idx = blockIdx.x * 256 + threadIdx.x;
  if (idx >= WS_ELEMS) return;
  float v;
  if (idx < O_E2W1)      { int l = idx;           v = e1w2[(l & 127) * 128 + (l >> 7)]; }
  else if (idx < O_E2W2) { int l = idx - O_E2W1;  v = e2w1[(l & 255) * 128 + (l >> 8)]; }
  else if (idx < O_E3W1) { int l = idx - O_E2W2;  v = e2w2[(l & 127) * 128 + (l >> 7)]; }
  else if (idx < O_E3W2) { int l = idx - O_E3W1;  v = e3w1[(l & 127) * 128 + (l >> 7)]; }
  else if (idx < O_E4W1) { int l = idx - O_E3W2;  v = e3w2[(l & 127) * 128 + (l >> 7)]; }
  else if (idx < O_E4W2) { int l = idx - O_E4W1;  v = e4w1[(l & 255) * 128 + (l >> 8)]; }
  else if (idx < O_DM2T0){ int l = idx - O_E4W2;  v = e4w2[(l & 127) * 128 + (l >> 7)]; }
  else if (idx < O_DM2T1){ int l = idx - O_DM2T0; v = dmsg2[(l & 127) * 128 + (l >> 7)]; }
  else if (idx < O_DO1)  { int l = idx - O_DM2T1; v = dmsg2[16384 + (l & 127) * 128 + (l >> 7)]; }
  else if (idx < O_DO2)  { int l = idx - O_DO1;   v = dout1[384 + (l & 127) * 128 + (l >> 7)]; }
  else if (idx < O_EWOUT){ int l = idx - O_DO2;   v = dout2[(l & 127) * 128 + (l >> 7)]; }
  else if (idx < O_DW3)  { int l = idx - O_EWOUT; int n = l >> 7;
                           v = (n < 2) ? ew_out[(l & 127) * 2 + n] : 0.f; }
  else if (idx < O_E1W1P){ int l = idx - O_DW3;   int n = l >> 7;
                           v = (n < 3) ? dout_w3[(l & 127) * 3 + n] : 0.f; }
  else if (idx < O_M1T0P){ int l = idx - O_E1W1P; int n = l >> 5, c = l & 31;
                           v = (c >= 3 && c < 6) ? e1w1[(c - 3) * 128 + n] : 0.f; }
  else if (idx < O_M1T1P){ int l = idx - O_M1T0P; int n = l >> 5, c = l & 31;
                           v = (c < 6) ? dmsg_w1[c * 128 + n] : 0.f; }
  else if (idx < O_DO1XP){ int l = idx - O_M1T1P; int n = l >> 5, c = l & 31;
                           v = (c < 6) ? dmsg_w1[768 + c * 128 + n] : 0.f; }
  else                   { int l = idx - O_DO1XP; int n = l >> 5, c = l & 31;
                           v = (c >= 3 && c < 6) ? dout1[(c - 3) * 128 + n] : 0.f; }
  ws[idx] = __float2bfloat16(v);
}

// 16 graphs/WG (96 rows), 512 threads = 8 waves, each wave owns 16 output cols.
// Same 71KB LDS as R7 -> still 2 blocks/CU, but 16 waves/CU instead of 8.
__global__ __launch_bounds__(512, 4) void nri_fused(
    const float* __restrict__ x,
    const float* __restrict__ e1b1, const float* __restrict__ e1b2,
    const float* __restrict__ e2b1, const float* __restrict__ e2b2,
    const float* __restrict__ e3b1, const float* __restrict__ e3b2,
    const float* __restrict__ e4b1, const float* __restrict__ e4b2,
    const float* __restrict__ eb_out,
    const float* __restrict__ dmsg_b1, const float* __restrict__ dmsg_b2,
    const float* __restrict__ dout_b1, const float* __restrict__ dout_b2,
    const float* __restrict__ dout_b3,
    const __bf16* __restrict__ wt, float* __restrict__ out)
{
  const int tid  = threadIdx.x;
  const int wave = tid >> 6;
  const int lane = tid & 63;
  const int nl   = lane & 15;
  const int quad = lane >> 4;
  const int colb = wave * 16 + nl;  // this wave's output column
  const int gx   = blockIdx.x * 288;

  __shared__ __align__(16) __hip_bfloat16 bufA[96 * LDW];
  __shared__ __align__(16) __hip_bfloat16 bufB[96 * LDW];
  __shared__ __align__(16) __hip_bfloat16 pxb[96 * PXW];
  __shared__ __align__(16) float biasL[16 * 128];
  __shared__ float rtw[192];
  __shared__ float xs[288];
  __shared__ float obuf[288];

  // ---- stage 0: stage x, bias table, pre_msg (all grid-stride: R6 lesson) ----
  for (int i = tid; i < 288; i += 512) xs[i] = x[gx + i];
  for (int i = tid; i < 2048; i += 512) {
    int row = i >> 7, c = i & 127;
    float v;
    switch (row) {
      case 0: v = e1b1[c]; break;   case 1: v = e1b2[c]; break;
      case 2: v = e2b1[c]; break;   case 3: v = e2b2[c]; break;
      case 4: v = e3b1[c]; break;   case 5: v = e3b2[c]; break;
      case 6: v = e4b1[c]; break;   case 7: v = e4b2[c]; break;
      case 8: v = dmsg_b1[c]; break;  case 9: v = dmsg_b1[128 + c]; break;
      case 10: v = dmsg_b2[c]; break; case 11: v = dmsg_b2[128 + c]; break;
      case 12: v = dout_b1[c]; break; case 13: v = dout_b2[c]; break;
      case 14: v = (c < 2) ? eb_out[c] : 0.f; break;
      default: v = (c < 3) ? dout_b3[c] : 0.f; break;
    }
    biasL[i] = v;
  }
  for (int i = tid; i < 96 * 32; i += 512) {
    int row = i >> 5, c = i & 31;
    int e = row % 6;
    float v = 0.f;
    if (c < 3)      { int rr = row + ((e == 5) ? -5 : 1); v = x[gx + rr * 3 + c]; }
    else if (c < 6) v = x[gx + row * 3 + (c - 3)];
    pxb[row * PXW + c] = __float2bfloat16(v);
  }
  __syncthreads();

  auto initb = [&](floatx4 (&a)[6], int brow) {
    float bv = biasL[brow * 128 + colb];
    floatx4 v = {bv, bv, bv, bv};
#pragma unroll
    for (int mt = 0; mt < 6; ++mt) a[mt] = v;
  };

  auto gemm128 = [&](floatx4 (&acc)[6], const __hip_bfloat16* in, const __bf16* w) {
    const __bf16* ab = (const __bf16*)(const void*)in;
    const __bf16* w0 = w + colb * 128 + quad * 8;
#pragma unroll
    for (int ks = 0; ks < 4; ++ks) {
      int kk = ks * 32 + quad * 8;
      bf16x8 b0 = *(const bf16x8*)(w0 + ks * 32);
#pragma unroll
      for (int mt = 0; mt < 6; ++mt) {
        bf16x8 a = *(const bf16x8*)(ab + (mt * 16 + nl) * LDW + kk);
        acc[mt] = __builtin_amdgcn_mfma_f32_16x16x32_bf16(a, b0, acc[mt], 0, 0, 0);
      }
    }
  };

  auto gemm256 = [&](floatx4 (&acc)[6], const __hip_bfloat16* in0, bool recv0,
                     const __hip_bfloat16* in1, const __bf16* w) {
    int rofs0[6], rofs1[6];
#pragma unroll
    for (int mt = 0; mt < 6; ++mt) {
      int r = mt * 16 + nl;
      rofs1[mt] = r * LDW;
      if (recv0) { int e = r % 6; r += (e == 5) ? -5 : 1; }
      rofs0[mt] = r * LDW;
    }
    const __bf16* ab0 = (const __bf16*)(const void*)in0;
    const __bf16* ab1 = (const __bf16*)(const void*)in1;
    const __bf16* w0 = w + colb * 256 + quad * 8;
#pragma unroll
    for (int ks = 0; ks < 8; ++ks) {
      int kk = (ks & 3) * 32 + quad * 8;
      const __bf16* ab = (ks < 4) ? ab0 : ab1;
      const int* rofs = (ks < 4) ? rofs0 : rofs1;
      bf16x8 b0 = *(const bf16x8*)(w0 + ks * 32);
#pragma unroll
      for (int mt = 0; mt < 6; ++mt) {
        bf16x8 a = *(const bf16x8*)(ab + rofs[mt] + kk);
        acc[mt] = __builtin_amdgcn_mfma_f32_16x16x32_bf16(a, b0, acc[mt], 0, 0, 0);
      }
    }
  };

  // K=32 GEMM: A from pxb, B from padded weight [128][32]
  auto gemm32 = [&](floatx4 (&acc)[6], int wofs) {
    const __bf16* pb = (const __bf16*)(const void*)pxb;
    bf16x8 b0 = *(const bf16x8*)(wt + wofs + colb * 32 + quad * 8);
#pragma unroll
    for (int mt = 0; mt < 6; ++mt) {
      bf16x8 a = *(const bf16x8*)(pb + (mt * 16 + nl) * PXW + quad * 8);
      acc[mt] = __builtin_amdgcn_mfma_f32_16x16x32_bf16(a, b0, acc[mt], 0, 0, 0);
    }
  };

  // act: 1=ELU 2=ReLU (bias already in acc)
  auto store_act = [&](floatx4 (&acc)[6], int act, __hip_bfloat16* ob) {
#pragma unroll
    for (int mt = 0; mt < 6; ++mt)
#pragma unroll
      for (int r = 0; r < 4; ++r) {
        float z = acc[mt][r];
        if (act == 1) z = (z > 0.f) ? z : (__expf(z) - 1.f);
        else z = fmaxf(z, 0.f);
        ob[(mt * 16 + quad * 4 + r) * LDW + colb] = __float2bfloat16(z);
      }
  };

  floatx4 acc[6];

  // s1: hh = ELU(x @ e1w1 + b) via K=32 MFMA
  initb(acc, 0); gemm32(acc, O_E1W1P); store_act(acc, 1, bufA);
  __syncthreads();
  // s2: h = ELU(. @ e1w2 + b)
  initb(acc, 1); gemm128(acc, bufA, wt + O_E1W2); store_act(acc, 1, bufB);
  __syncthreads();
  // s3: ELU([h_recv|h] @ e2w1 + b)
  initb(acc, 2); gemm256(acc, bufB, true, bufB, wt + O_E2W1); store_act(acc, 1, bufA);
  __syncthreads();
  // s4: he = ELU(. @ e2w2 + b) -> bufB (keep)
  initb(acc, 3); gemm128(acc, bufA, wt + O_E2W2); store_act(acc, 1, bufB);
  __syncthreads();
  // s5: ELU(he @ e3w1 + b) -> bufA
  initb(acc, 4); gemm128(acc, bufB, wt + O_E3W1); store_act(acc, 1, bufA);
  __syncthreads();
  // s6: h2 = ELU(. @ e3w2 + b) -> bufA in-place
  initb(acc, 5); gemm128(acc, bufA, wt + O_E3W2);
  __syncthreads();
  store_act(acc, 1, bufA);
  __syncthreads();
  // s7: ELU([h2|he] @ e4w1 + b) -> bufA in-place
  initb(acc, 6); gemm256(acc, bufA, false, bufB, wt + O_E4W1);
  __syncthreads();
  store_act(acc, 1, bufA);
  __syncthreads();
  // s8: h3 = ELU(. @ e4w2 + b) -> bufB
  initb(acc, 7); gemm128(acc, bufA, wt + O_E4W2); store_act(acc, 1, bufB);
  __syncthreads();

  // s9: logits via N=16-padded MFMA tail (waves 0..5, one row-tile each)
  if (wave < 6) {
    int tile = wave;
    float bv = biasL[14 * 128 + nl];
    floatx4 lg = {bv, bv, bv, bv};
    const __bf16* ab = (const __bf16*)(const void*)bufB;
    const __bf16* wp = wt + O_EWOUT + nl * 128 + quad * 8;
#pragma unroll
    for (int ks = 0; ks < 4; ++ks) {
      bf16x8 a = *(const bf16x8*)(ab + (tile * 16 + nl) * LDW + ks * 32 + quad * 8);
      bf16x8 b = *(const bf16x8*)(wp + ks * 32);
      lg = __builtin_amdgcn_mfma_f32_16x16x32_bf16(a, b, lg, 0, 0, 0);
    }
    if (nl < 2) {
#pragma unroll
      for (int r = 0; r < 4; ++r)
        rtw[(tile * 16 + quad * 4 + r) * 2 + nl] = lg[r];
    }
  }
  __syncthreads();

  // s10: softmax (tid<96) + m1 both types via K=32 MFMA: t0->bufA, t1->bufB
  if (tid < 96) {
    float l0 = rtw[tid * 2], l1 = rtw[tid * 2 + 1];
    float mx = fmaxf(l0, l1);
    float ea = __expf(l0 - mx), eb = __expf(l1 - mx);
    float inv = 1.f / (ea + eb);
    rtw[tid * 2] = ea * inv; rtw[tid * 2 + 1] = eb * inv;
  }
  {
    floatx4 acc1[6];
    initb(acc, 8);  gemm32(acc, O_M1T0P);  store_act(acc, 2, bufA);
    initb(acc1, 9); gemm32(acc1, O_M1T1P); store_act(acc1, 2, bufB);
    __syncthreads();

    // s11: msg = rt0*relu(dm2t0 . m1t0) + rt1*relu(dm2t1 . m1t1)
    initb(acc, 10);  gemm128(acc, bufA, wt + O_DM2T0);
    initb(acc1, 11); gemm128(acc1, bufB, wt + O_DM2T1);
#pragma unroll
    for (int mt = 0; mt < 6; ++mt)
#pragma unroll
      for (int r = 0; r < 4; ++r) {
        int row = mt * 16 + quad * 4 + r;
        float r0 = rtw[row * 2], r1 = rtw[row * 2 + 1];
        acc[mt][r] = r0 * fmaxf(acc[mt][r], 0.f) + r1 * fmaxf(acc1[mt][r], 0.f);
      }
  }
  __syncthreads();

  // s12: agg (edge e -> node (e+1)%6) -> bufA
#pragma unroll
  for (int mt = 0; mt < 6; ++mt)
#pragma unroll
    for (int r = 0; r < 4; ++r) {
      int row = mt * 16 + quad * 4 + r;
      int e = row % 6;
      int orow = row + ((e == 5) ? -5 : 1);
      bufA[orow * LDW + colb] = __float2bfloat16(acc[mt][r]);
    }
  __syncthreads();

  // s13: p1 = relu([x|agg] @ d_out_w1 + b) -> bufB  (K=128 MFMA + K=32 MFMA)
  initb(acc, 12); gemm128(acc, bufA, wt + O_DO1); gemm32(acc, O_DO1XP);
  store_act(acc, 2, bufB);
  __syncthreads();
  // s14: p2 = relu(. @ d_out_w2 + b) -> bufA
  initb(acc, 13); gemm128(acc, bufB, wt + O_DO2); store_act(acc, 2, bufA);
  __syncthreads();

  // s15: out = x + p2 @ d_out_w3 + b3 via N=16-padded MFMA tail (waves 0..5)
  if (wave < 6) {
    int tile = wave;
    float bv = biasL[15 * 128 + nl];
    floatx4 d = {bv, bv, bv, bv};
    const __bf16* ab = (const __bf16*)(const void*)bufA;
    const __bf16* wp = wt + O_DW3 + nl * 128 + quad * 8;
#pragma unroll
    for (int ks = 0; ks < 4; ++ks) {
      bf16x8 a = *(const bf16x8*)(ab + (tile * 16 + nl) * LDW + ks * 32 + quad * 8);
      bf16x8 b = *(const bf16x8*)(wp + ks * 32);
      d = __builtin_amdgcn_mfma_f32_16x16x32_bf16(a, b, d, 0, 0, 0);
    }
    if (nl < 3) {
#pragma unroll
      for (int r = 0; r < 4; ++r) {
        int row = tile * 16 + quad * 4 + r;
        obuf[row * 3 + nl] = xs[row * 3 + nl] + d[r];
      }
    }
  }
  __syncthreads();
  for (int i = tid; i < 288; i += 512) out[gx + i] = obuf[i];
}

extern "C" void kernel_launch(void* const* d_in, const int* in_sizes, int n_in,
                              void* d_out, int out_size, void* d_ws, size_t ws_size,
                              hipStream_t stream) {
  const float* x       = (const float*)d_in[0];
  const float* e1w1    = (const float*)d_in[3];
  const float* e1b1    = (const float*)d_in[4];
  const float* e1w2    = (const float*)d_in[5];
  const float* e1b2    = (const float*)d_in[6];
  const float* e2w1    = (const float*)d_in[7];
  const float* e2b1    = (const float*)d_in[8];
  const float* e2w2    = (const float*)d_in[9];
  const float* e2b2    = (const float*)d_in[10];
  const float* e3w1    = (const float*)d_in[11];
  const float* e3b1    = (const float*)d_in[12];
  const float* e3w2    = (const float*)d_in[13];
  const float* e3b2    = (const float*)d_in[14];
  const float* e4w1    = (const float*)d_in[15];
  const float* e4b1    = (const float*)d_in[16];
  const float* e4w2    = (const float*)d_in[17];
  const float* e4b2    = (const float*)d_in[18];
  const float* ew_out  = (const float*)d_in[19];
  const float* eb_out  = (const float*)d_in[20];
  const float* dmsg_w1 = (const float*)d_in[21];
  const float* dmsg_b1 = (const float*)d_in[22];
  const float* dmsg_w2 = (const float*)d_in[23];
  const float* dmsg_b2 = (const float*)d_in[24];
  const float* dout_w1 = (const float*)d_in[25];
  const float* dout_b1 = (const float*)d_in[26];
  const float* dout_w2 = (const float*)d_in[27];
  const float* dout_b2 = (const float*)d_in[28];
  const float* dout_w3 = (const float*)d_in[29];
  const float* dout_b3 = (const float*)d_in[30];

  prep_kernel<<<(WS_ELEMS + 255) / 256, 256, 0, stream>>>(
      e1w2, e2w1, e2w2, e3w1, e3w2, e4w1, e4w2, dmsg_w2, dout_w1, dout_w2,
      ew_out, dout_w3, e1w1, dmsg_w1, (__hip_bfloat16*)d_ws);

  nri_fused<<<32768 / 16, 512, 0, stream>>>(
      x, e1b1, e1b2, e2b1, e2b2, e3b1, e3b2, e4b1, e4b2, eb_out,
      dmsg_b1, dmsg_b2, dout_b1, dout_b2, dout_b3,
      (const __bf16*)d_ws, (float*)d_out);
}